// Round 3
// baseline (438.943 us; speedup 1.0000x reference)
//
#include <hip/hip_runtime.h>
#include <math.h>

// ---- problem constants ----
#define TT   5
#define CAM  4
#define TC   20
#define BB   2
#define CF   32
#define HC   30
#define WC   40
#define MM   1200
#define NMAX 19
#define EPSF 1e-12f
#define RT   75      // 16-row tiles per item (1200/16)
#define JT   75      // 16-col tiles per item

typedef __attribute__((ext_vector_type(8))) short short8v;   // 8 bf16 (4 VGPR)
typedef __attribute__((ext_vector_type(4))) float float4v;

__device__ inline unsigned short f2bf(float x) {
  unsigned int u = __float_as_uint(x);
  unsigned int r = (u + 0x7FFFu + ((u >> 16) & 1u)) >> 16;  // RNE
  return (unsigned short)r;
}
__device__ inline float bf2f(unsigned short h) {
  return __uint_as_float(((unsigned int)h) << 16);
}

// ------------------------------------------------------------------
// K1: channel-L2-normalize, split into bf16 hi/lo, store MFMA-ready:
// dsp[tcb][sec][pix] (16B each), sec = (hilo ? 4 : 0) + kquarter.
// Extra block column (blockIdx.x == TC*BB) fills the coord table:
// ctab[j] = (cx, cy, cx^2+cy^2, 0).
// ------------------------------------------------------------------
__global__ void k_split(const float* __restrict__ pred, short8v* __restrict__ dsp,
                        float4* __restrict__ ctab) {
  int tb = blockIdx.x;
  int tid = threadIdx.x;
  if (tb == TC * BB) {
    int idx = blockIdx.y * 240 + tid;
    if (tid < 240 && idx < MM) {
      float cx = (float)((idx % WC) * 8);
      float cy = (float)((idx / WC) * 8);
      ctab[idx] = make_float4(cx, cy, cx * cx + cy * cy, 0.f);
    }
    return;
  }
  const float* src = pred + (size_t)tb * CF * MM;
  short8v*     dst = dsp  + (size_t)tb * 8 * MM;
  int pix = blockIdx.y * 240 + tid;
  if (tid >= 240 || pix >= MM) return;
  float v[CF]; float ss = 0.f;
#pragma unroll
  for (int c = 0; c < CF; ++c) { float x = src[c * MM + pix]; v[c] = x; ss = fmaf(x, x, ss); }
  float inv = 1.f / fmaxf(sqrtf(ss), EPSF);
  unsigned short hi[CF], lo[CF];
#pragma unroll
  for (int c = 0; c < CF; ++c) {
    float xn = v[c] * inv;
    unsigned short h = f2bf(xn);
    hi[c] = h;
    lo[c] = f2bf(xn - bf2f(h));
  }
#pragma unroll
  for (int s = 0; s < 4; ++s) {
    short8v oh, ol;
#pragma unroll
    for (int e = 0; e < 8; ++e) { oh[e] = (short)hi[s*8+e]; ol[e] = (short)lo[s*8+e]; }
    dst[(size_t)s * MM + pix]       = oh;
    dst[(size_t)(4 + s) * MM + pix] = ol;
  }
}

// ------------------------------------------------------------------
// K2: homography (f64) + warped coords per (iv,n,b)
// ------------------------------------------------------------------
__device__ inline void rodrigues_d(const double rv[3], double R[9]) {
  double th = sqrt(rv[0]*rv[0] + rv[1]*rv[1] + rv[2]*rv[2]);
  double thc = fmax(th, 1e-12);
  double kx = rv[0] / thc, ky = rv[1] / thc, kz = rv[2] / thc;
  double st = sin(th), ct = cos(th);
  double Km[9] = { 0.0, -kz,  ky,  kz, 0.0, -kx,  -ky, kx, 0.0 };
  double K2[9];
  for (int r = 0; r < 3; ++r)
    for (int c = 0; c < 3; ++c)
      K2[r*3+c] = Km[r*3+0]*Km[0*3+c] + Km[r*3+1]*Km[1*3+c] + Km[r*3+2]*Km[2*3+c];
  for (int r = 0; r < 3; ++r)
    for (int c = 0; c < 3; ++c)
      R[r*3+c] = (r == c ? 1.0 : 0.0) + st * Km[r*3+c] + (1.0 - ct) * K2[r*3+c];
}
__device__ inline void mm3(const double* A, const double* B, double* C) {
  for (int r = 0; r < 3; ++r)
    for (int c = 0; c < 3; ++c)
      C[r*3+c] = A[r*3+0]*B[0*3+c] + A[r*3+1]*B[1*3+c] + A[r*3+2]*B[2*3+c];
}

__global__ void k_warp(const float* __restrict__ rv_, const float* __restrict__ tv_,
                       const float* __restrict__ nts_, const float* __restrict__ dep_,
                       const float* __restrict__ Ks_, const float* __restrict__ Kin_,
                       const float* __restrict__ osz_, const int* __restrict__ ivl,
                       float2* __restrict__ warped) {
  int slot = blockIdx.x;
  int ivi = slot / (NMAX * BB);
  int rem = slot % (NMAX * BB);
  int n = rem / BB, b = rem % BB;
  int iv = ivl[ivi];
  if (n >= TC - iv) return;
  int q0 = n, q1 = n + iv;
  int t0 = q0 / CAM, c0 = q0 % CAM;
  int t1 = q1 / CAM, c1 = q1 % CAM;
  size_t e0 = (size_t)(t0 * BB + b) * CAM + c0;
  size_t e1 = (size_t)(t1 * BB + b) * CAM + c1;

  double rv0[3], tv0[3], rv1[3], tv1[3], nv[3];
  for (int k = 0; k < 3; ++k) {
    rv0[k] = rv_[e0*3 + k]; tv0[k] = tv_[e0*3 + k];
    rv1[k] = rv_[e1*3 + k]; tv1[k] = tv_[e1*3 + k];
    nv[k]  = nts_[e0*3 + k];
  }
  double d = dep_[e0];
  double K9[9], Ki9[9];
  for (int k = 0; k < 9; ++k) { K9[k] = Ks_[e0*9 + k]; Ki9[k] = Kin_[e0*9 + k]; }

  double R0[9], R1[9], R[9];
  rodrigues_d(rv0, R0);
  rodrigues_d(rv1, R1);
  for (int r = 0; r < 3; ++r)
    for (int c = 0; c < 3; ++c)
      R[r*3+c] = R1[r*3+0]*R0[c*3+0] + R1[r*3+1]*R0[c*3+1] + R1[r*3+2]*R0[c*3+2];
  double tvec[3];
  for (int r = 0; r < 3; ++r)
    tvec[r] = tv1[r] - (R[r*3+0]*tv0[0] + R[r*3+1]*tv0[1] + R[r*3+2]*tv0[2]);
  double Mid[9];
  for (int r = 0; r < 3; ++r)
    for (int c = 0; c < 3; ++c)
      Mid[r*3+c] = R[r*3+c] - tvec[r] * nv[c] / d;
  double T1[9], Hm[9];
  mm3(K9, Mid, T1);
  mm3(T1, Ki9, Hm);

  double osz0 = osz_[e0*2 + 0], osz1 = osz_[e0*2 + 1];
  double s0 = 240.0 / osz0, s1 = 320.0 / osz1;
  double sv[3] = { s1, s0, 1.0 };
  double Hs[9];
  for (int r = 0; r < 3; ++r)
    for (int c = 0; c < 3; ++c)
      Hs[r*3+c] = Hm[r*3+c] * sv[r] / sv[c];

  float2* wout = warped + (size_t)slot * MM;
  for (int cell = threadIdx.x; cell < MM; cell += blockDim.x) {
    double x = (double)((cell % WC) * 8);
    double y = (double)((cell / WC) * 8);
    double wx = Hs[0]*x + Hs[1]*y + Hs[2];
    double wy = Hs[3]*x + Hs[4]*y + Hs[5];
    double wz = Hs[6]*x + Hs[7]*y + Hs[8];
    float z = (float)wz;
    if (fabsf(z) < 1e-8f) z = 1e-8f;
    wout[cell] = make_float2((float)wx / z, (float)wy / z);
  }
}

__device__ inline bool decode_slot(int slot, const int* ivl, int& n, int& b, int& iv) {
  int ivi = slot / (NMAX * BB);
  int rem = slot % (NMAX * BB);
  n = rem / BB; b = rem % BB;
  iv = ivl[ivi];
  return n < TC - iv;
}

// 2-term bf16-split MFMA: S_tile = Ah*Bh + Ah*Bl + Al*Bh
__device__ inline float4v s_tile(short8v ah, short8v al, short8v bh, short8v bl) {
  float4v acc = {0.f, 0.f, 0.f, 0.f};
  acc = __builtin_amdgcn_mfma_f32_16x16x32_bf16(ah, bh, acc, 0, 0, 0);
  acc = __builtin_amdgcn_mfma_f32_16x16x32_bf16(ah, bl, acc, 0, 0, 0);
  acc = __builtin_amdgcn_mfma_f32_16x16x32_bf16(al, bh, acc, 0, 0, 0);
  return acc;
}

// ------------------------------------------------------------------
// K3: inverse row norms. wave = 16 rows; double-buffered B loads.
// ------------------------------------------------------------------
__global__ void __launch_bounds__(256) k_rnorm(const short8v* __restrict__ dsp,
                                               const int* __restrict__ ivl,
                                               float* __restrict__ irn) {
  int slot = blockIdx.x;
  int n, b, iv;
  if (!decode_slot(slot, ivl, n, b, iv)) return;
  int wid = threadIdx.x >> 6, lane = threadIdx.x & 63;
  int rowtile = blockIdx.y * 4 + wid;
  if (rowtile >= RT) return;
  int q = lane >> 4, li = lane & 15;
  const short8v* D0 = dsp + (size_t)(n * BB + b) * 8 * MM;
  const short8v* B0 = dsp + (size_t)((n + iv) * BB + b) * 8 * MM + (size_t)q * MM + li;
  const short8v* B4 = B0 + 4 * MM;
  int row16 = rowtile * 16;
  short8v ah = D0[(size_t)q * MM + row16 + li];
  short8v al = D0[(size_t)(q + 4) * MM + row16 + li];
  short8v bh = B0[0], bl = B4[0];
  float4v racc = {0.f, 0.f, 0.f, 0.f};
#pragma unroll 3
  for (int jt = 0; jt < JT - 1; ++jt) {
    short8v bhn = B0[(jt + 1) * 16];
    short8v bln = B4[(jt + 1) * 16];
    float4v acc = s_tile(ah, al, bh, bl);
#pragma unroll
    for (int r = 0; r < 4; ++r) { float t = fmaxf(acc[r], 0.f); racc[r] = fmaf(t, t, racc[r]); }
    bh = bhn; bl = bln;
  }
  {
    float4v acc = s_tile(ah, al, bh, bl);
#pragma unroll
    for (int r = 0; r < 4; ++r) { float t = fmaxf(acc[r], 0.f); racc[r] = fmaf(t, t, racc[r]); }
  }
#pragma unroll
  for (int m = 1; m <= 8; m <<= 1)
#pragma unroll
    for (int r = 0; r < 4; ++r) racc[r] += __shfl_xor(racc[r], m);
  if (li == 0) {
#pragma unroll
    for (int r = 0; r < 4; ++r)
      irn[(size_t)slot * MM + row16 + q * 4 + r] = 1.f / fmaxf(sqrtf(racc[r]), EPSF);
  }
}

// ------------------------------------------------------------------
// K4: inverse col norms of (relu(S)/rnorm_i). wave = 16 cols (j).
// ------------------------------------------------------------------
__global__ void __launch_bounds__(256) k_cnorm(const short8v* __restrict__ dsp,
                                               const int* __restrict__ ivl,
                                               const float* __restrict__ irn,
                                               float* __restrict__ icn) {
  int slot = blockIdx.x;
  int n, b, iv;
  if (!decode_slot(slot, ivl, n, b, iv)) return;
  int wid = threadIdx.x >> 6, lane = threadIdx.x & 63;
  int coltile = blockIdx.y * 4 + wid;
  if (coltile >= RT) return;
  int q = lane >> 4, li = lane & 15;
  const short8v* D1 = dsp + (size_t)((n + iv) * BB + b) * 8 * MM;
  const short8v* B0 = dsp + (size_t)(n * BB + b) * 8 * MM + (size_t)q * MM + li;
  const short8v* B4 = B0 + 4 * MM;
  int col16 = coltile * 16;
  short8v ah = D1[(size_t)q * MM + col16 + li];
  short8v al = D1[(size_t)(q + 4) * MM + col16 + li];
  const float* irnS = irn + (size_t)slot * MM + li;
  short8v bh = B0[0], bl = B4[0];
  float ir = irnS[0];
  float4v cacc = {0.f, 0.f, 0.f, 0.f};
#pragma unroll 3
  for (int it = 0; it < JT - 1; ++it) {
    short8v bhn = B0[(it + 1) * 16];
    short8v bln = B4[(it + 1) * 16];
    float irn_ = irnS[(it + 1) * 16];
    float4v acc = s_tile(ah, al, bh, bl);
#pragma unroll
    for (int r = 0; r < 4; ++r) { float t = fmaxf(acc[r], 0.f) * ir; cacc[r] = fmaf(t, t, cacc[r]); }
    bh = bhn; bl = bln; ir = irn_;
  }
  {
    float4v acc = s_tile(ah, al, bh, bl);
#pragma unroll
    for (int r = 0; r < 4; ++r) { float t = fmaxf(acc[r], 0.f) * ir; cacc[r] = fmaf(t, t, cacc[r]); }
  }
#pragma unroll
  for (int m = 1; m <= 8; m <<= 1)
#pragma unroll
    for (int r = 0; r < 4; ++r) cacc[r] += __shfl_xor(cacc[r], m);
  if (li == 0) {
#pragma unroll
    for (int r = 0; r < 4; ++r)
      icn[(size_t)slot * MM + col16 + q * 4 + r] = 1.f / fmaxf(sqrtf(cacc[r]), EPSF);
  }
}

// ------------------------------------------------------------------
// K5: loss. wave = 16 rows (i); expanded-distance mask epilogue.
// ------------------------------------------------------------------
__global__ void __launch_bounds__(256) k_loss(const short8v* __restrict__ dsp,
                                              const int* __restrict__ ivl,
                                              const float* __restrict__ irn,
                                              const float* __restrict__ icn,
                                              const float2* __restrict__ warped,
                                              const float4* __restrict__ ctab,
                                              double* __restrict__ partials) {
  int slot = blockIdx.x;
  int wid = threadIdx.x >> 6, lane = threadIdx.x & 63;
  int rowtile = blockIdx.y * 4 + wid;
  int n, b, iv;
  bool valid = decode_slot(slot, ivl, n, b, iv);
  if (!valid) {
    if (rowtile < RT && lane == 0) partials[(size_t)slot * RT + rowtile] = 0.0;
    return;
  }
  if (rowtile >= RT) return;
  int q = lane >> 4, li = lane & 15;
  const short8v* D0 = dsp + (size_t)(n * BB + b) * 8 * MM;
  const short8v* B0 = dsp + (size_t)((n + iv) * BB + b) * 8 * MM + (size_t)q * MM + li;
  const short8v* B4 = B0 + 4 * MM;
  int row16 = rowtile * 16;
  short8v ah = D0[(size_t)q * MM + row16 + li];
  short8v al = D0[(size_t)(q + 4) * MM + row16 + li];
  float irn4[4], wxm[4], wym[4], Qr[4];
#pragma unroll
  for (int r = 0; r < 4; ++r) {
    int row = row16 + q * 4 + r;
    irn4[r] = irn[(size_t)slot * MM + row];
    float2 wp = warped[(size_t)slot * MM + row];
    wxm[r] = -2.f * wp.x;
    wym[r] = -2.f * wp.y;
    Qr[r]  = fmaf(-wp.x, wp.x, fmaf(-wp.y, wp.y, 56.25f));
  }
  const float*  icnS = icn + (size_t)slot * MM + li;
  const float4* ctS  = ctab + li;
  short8v bh = B0[0], bl = B4[0];
  float ic = icnS[0];
  float4 ct = ctS[0];
  float lacc = 0.f;
#pragma unroll 3
  for (int jt = 0; jt < JT - 1; ++jt) {
    int o = (jt + 1) * 16;
    short8v bhn = B0[o];
    short8v bln = B4[o];
    float icn_ = icnS[o];
    float4 ctn = ctS[o];
    float4v acc = s_tile(ah, al, bh, bl);
#pragma unroll
    for (int r = 0; r < 4; ++r) {
      float s  = fmaxf(acc[r], 0.f);
      float Dv = s * ic * irn4[r];
      float pm = fmaf(Dv, -0.05f, 0.05f);
      float nm = Dv - 0.2f;
      float t2 = fmaf(ct.y, wym[r], fmaf(ct.x, wxm[r], ct.z));
      float c  = (t2 <= Qr[r]) ? pm : nm;
      lacc += fmaxf(c, 0.f);
    }
    bh = bhn; bl = bln; ic = icn_; ct = ctn;
  }
  {
    float4v acc = s_tile(ah, al, bh, bl);
#pragma unroll
    for (int r = 0; r < 4; ++r) {
      float s  = fmaxf(acc[r], 0.f);
      float Dv = s * ic * irn4[r];
      float pm = fmaf(Dv, -0.05f, 0.05f);
      float nm = Dv - 0.2f;
      float t2 = fmaf(ct.y, wym[r], fmaf(ct.x, wxm[r], ct.z));
      float c  = (t2 <= Qr[r]) ? pm : nm;
      lacc += fmaxf(c, 0.f);
    }
  }
#pragma unroll
  for (int off = 32; off > 0; off >>= 1) lacc += __shfl_xor(lacc, off);
  if (lane == 0) partials[(size_t)slot * RT + rowtile] = (double)lacc;
}

// ------------------------------------------------------------------
// K6: final reduction
// ------------------------------------------------------------------
__global__ void k_final(const double* __restrict__ partials, const int* __restrict__ ivl,
                        int niv, float* __restrict__ out) {
  int lane = threadIdx.x; // 64 threads
  double total = 0.0;
  for (int ivi = 0; ivi < niv; ++ivi) {
    double local = 0.0;
    int base = ivi * NMAX * BB * RT;
    for (int p = lane; p < NMAX * BB * RT; p += 64) local += partials[base + p];
    for (int off = 32; off > 0; off >>= 1) local += __shfl_down(local, off);
    int N = TC - ivl[ivi];
    total += local / ((double)N * BB * (double)MM * (double)MM);
  }
  if (lane == 0) out[0] = (float)(total / (double)niv);
}

// ------------------------------------------------------------------
extern "C" void kernel_launch(void* const* d_in, const int* in_sizes, int n_in,
                              void* d_out, int out_size, void* d_ws, size_t ws_size,
                              hipStream_t stream) {
  const float* pred = (const float*)d_in[0];
  const float* rv   = (const float*)d_in[1];
  const float* tv   = (const float*)d_in[2];
  const float* nts  = (const float*)d_in[3];
  const float* dep  = (const float*)d_in[4];
  const float* Ks   = (const float*)d_in[5];
  const float* Kin  = (const float*)d_in[6];
  const float* osz  = (const float*)d_in[7];
  const int*   ivl  = (const int*)d_in[8];
  int niv = in_sizes[8];
  int slots = niv * NMAX * BB;

  char* ws = (char*)d_ws;
  size_t off = 0;
  short8v* dsp = (short8v*)(ws + off); off += (size_t)TC * BB * 8 * MM * 16;
  float2* warped = (float2*)(ws + off); off += (size_t)slots * MM * 8;
  float* irn = (float*)(ws + off);     off += (size_t)slots * MM * 4;
  float* icn = (float*)(ws + off);     off += (size_t)slots * MM * 4;
  off = (off + 255) & ~(size_t)255;
  double* partials = (double*)(ws + off); off += (size_t)slots * RT * 8;
  float4* ctab = (float4*)(ws + off);  off += (size_t)MM * 16;

  hipLaunchKernelGGL(k_split, dim3(TC * BB + 1, 5), dim3(256), 0, stream, pred, dsp, ctab);
  hipLaunchKernelGGL(k_warp, dim3(slots), dim3(64), 0, stream,
                     rv, tv, nts, dep, Ks, Kin, osz, ivl, warped);
  dim3 grid(slots, (RT + 3) / 4);
  hipLaunchKernelGGL(k_rnorm, grid, dim3(256), 0, stream, dsp, ivl, irn);
  hipLaunchKernelGGL(k_cnorm, grid, dim3(256), 0, stream, dsp, ivl, irn, icn);
  hipLaunchKernelGGL(k_loss, grid, dim3(256), 0, stream,
                     dsp, ivl, irn, icn, warped, ctab, partials);
  hipLaunchKernelGGL(k_final, dim3(1), dim3(64), 0, stream, partials, ivl, niv, (float*)d_out);
}

// Round 4
// 156.084 us; speedup vs baseline: 2.8122x; 2.8122x over previous
//
#include <hip/hip_runtime.h>
#include <math.h>

// ---- problem constants ----
#define TT   5
#define CAM  4
#define TC   20
#define BB   2
#define CF   32
#define HC   30
#define WC   40
#define MM   1200
#define NMAX 19
#define EPSF 1e-12f
#define RT   75      // 16-row tiles per item (1200/16)
#define JT   75      // 16-col tiles per item

typedef __attribute__((ext_vector_type(8))) short short8v;   // 8 bf16 (4 VGPR)
typedef __attribute__((ext_vector_type(4))) float float4v;

__device__ inline unsigned short f2bf(float x) {
  unsigned int u = __float_as_uint(x);
  unsigned int r = (u + 0x7FFFu + ((u >> 16) & 1u)) >> 16;  // RNE
  return (unsigned short)r;
}
__device__ inline float bf2f(unsigned short h) {
  return __uint_as_float(((unsigned int)h) << 16);
}

// ------------------------------------------------------------------
// K1: channel-L2-normalize, split into bf16 hi/lo, store MFMA-ready:
// dsp[tcb][sec][pix] (16B each), sec = (hilo ? 4 : 0) + kquarter.
// Extra block column (blockIdx.x == TC*BB) fills the coord table:
// ctab[j] = (cx, cy, cx^2+cy^2, 0).
// ------------------------------------------------------------------
__global__ void k_split(const float* __restrict__ pred, short8v* __restrict__ dsp,
                        float4* __restrict__ ctab) {
  int tb = blockIdx.x;
  int tid = threadIdx.x;
  if (tb == TC * BB) {
    int idx = blockIdx.y * 240 + tid;
    if (tid < 240 && idx < MM) {
      float cx = (float)((idx % WC) * 8);
      float cy = (float)((idx / WC) * 8);
      ctab[idx] = make_float4(cx, cy, cx * cx + cy * cy, 0.f);
    }
    return;
  }
  const float* src = pred + (size_t)tb * CF * MM;
  short8v*     dst = dsp  + (size_t)tb * 8 * MM;
  int pix = blockIdx.y * 240 + tid;
  if (tid >= 240 || pix >= MM) return;
  float v[CF]; float ss = 0.f;
#pragma unroll
  for (int c = 0; c < CF; ++c) { float x = src[c * MM + pix]; v[c] = x; ss = fmaf(x, x, ss); }
  float inv = 1.f / fmaxf(sqrtf(ss), EPSF);
  unsigned short hi[CF], lo[CF];
#pragma unroll
  for (int c = 0; c < CF; ++c) {
    float xn = v[c] * inv;
    unsigned short h = f2bf(xn);
    hi[c] = h;
    lo[c] = f2bf(xn - bf2f(h));
  }
#pragma unroll
  for (int s = 0; s < 4; ++s) {
    short8v oh, ol;
#pragma unroll
    for (int e = 0; e < 8; ++e) { oh[e] = (short)hi[s*8+e]; ol[e] = (short)lo[s*8+e]; }
    dst[(size_t)s * MM + pix]       = oh;
    dst[(size_t)(4 + s) * MM + pix] = ol;
  }
}

// ------------------------------------------------------------------
// K2: homography (f64) + warped coords per (iv,n,b)
// ------------------------------------------------------------------
__device__ inline void rodrigues_d(const double rv[3], double R[9]) {
  double th = sqrt(rv[0]*rv[0] + rv[1]*rv[1] + rv[2]*rv[2]);
  double thc = fmax(th, 1e-12);
  double kx = rv[0] / thc, ky = rv[1] / thc, kz = rv[2] / thc;
  double st = sin(th), ct = cos(th);
  double Km[9] = { 0.0, -kz,  ky,  kz, 0.0, -kx,  -ky, kx, 0.0 };
  double K2[9];
  for (int r = 0; r < 3; ++r)
    for (int c = 0; c < 3; ++c)
      K2[r*3+c] = Km[r*3+0]*Km[0*3+c] + Km[r*3+1]*Km[1*3+c] + Km[r*3+2]*Km[2*3+c];
  for (int r = 0; r < 3; ++r)
    for (int c = 0; c < 3; ++c)
      R[r*3+c] = (r == c ? 1.0 : 0.0) + st * Km[r*3+c] + (1.0 - ct) * K2[r*3+c];
}
__device__ inline void mm3(const double* A, const double* B, double* C) {
  for (int r = 0; r < 3; ++r)
    for (int c = 0; c < 3; ++c)
      C[r*3+c] = A[r*3+0]*B[0*3+c] + A[r*3+1]*B[1*3+c] + A[r*3+2]*B[2*3+c];
}

__global__ void k_warp(const float* __restrict__ rv_, const float* __restrict__ tv_,
                       const float* __restrict__ nts_, const float* __restrict__ dep_,
                       const float* __restrict__ Ks_, const float* __restrict__ Kin_,
                       const float* __restrict__ osz_, const int* __restrict__ ivl,
                       float2* __restrict__ warped) {
  int slot = blockIdx.x;
  int ivi = slot / (NMAX * BB);
  int rem = slot % (NMAX * BB);
  int n = rem / BB, b = rem % BB;
  int iv = ivl[ivi];
  if (n >= TC - iv) return;
  int q0 = n, q1 = n + iv;
  int t0 = q0 / CAM, c0 = q0 % CAM;
  int t1 = q1 / CAM, c1 = q1 % CAM;
  size_t e0 = (size_t)(t0 * BB + b) * CAM + c0;
  size_t e1 = (size_t)(t1 * BB + b) * CAM + c1;

  double rv0[3], tv0[3], rv1[3], tv1[3], nv[3];
  for (int k = 0; k < 3; ++k) {
    rv0[k] = rv_[e0*3 + k]; tv0[k] = tv_[e0*3 + k];
    rv1[k] = rv_[e1*3 + k]; tv1[k] = tv_[e1*3 + k];
    nv[k]  = nts_[e0*3 + k];
  }
  double d = dep_[e0];
  double K9[9], Ki9[9];
  for (int k = 0; k < 9; ++k) { K9[k] = Ks_[e0*9 + k]; Ki9[k] = Kin_[e0*9 + k]; }

  double R0[9], R1[9], R[9];
  rodrigues_d(rv0, R0);
  rodrigues_d(rv1, R1);
  for (int r = 0; r < 3; ++r)
    for (int c = 0; c < 3; ++c)
      R[r*3+c] = R1[r*3+0]*R0[c*3+0] + R1[r*3+1]*R0[c*3+1] + R1[r*3+2]*R0[c*3+2];
  double tvec[3];
  for (int r = 0; r < 3; ++r)
    tvec[r] = tv1[r] - (R[r*3+0]*tv0[0] + R[r*3+1]*tv0[1] + R[r*3+2]*tv0[2]);
  double Mid[9];
  for (int r = 0; r < 3; ++r)
    for (int c = 0; c < 3; ++c)
      Mid[r*3+c] = R[r*3+c] - tvec[r] * nv[c] / d;
  double T1[9], Hm[9];
  mm3(K9, Mid, T1);
  mm3(T1, Ki9, Hm);

  double osz0 = osz_[e0*2 + 0], osz1 = osz_[e0*2 + 1];
  double s0 = 240.0 / osz0, s1 = 320.0 / osz1;
  double sv[3] = { s1, s0, 1.0 };
  double Hs[9];
  for (int r = 0; r < 3; ++r)
    for (int c = 0; c < 3; ++c)
      Hs[r*3+c] = Hm[r*3+c] * sv[r] / sv[c];

  float2* wout = warped + (size_t)slot * MM;
  for (int cell = threadIdx.x; cell < MM; cell += blockDim.x) {
    double x = (double)((cell % WC) * 8);
    double y = (double)((cell / WC) * 8);
    double wx = Hs[0]*x + Hs[1]*y + Hs[2];
    double wy = Hs[3]*x + Hs[4]*y + Hs[5];
    double wz = Hs[6]*x + Hs[7]*y + Hs[8];
    float z = (float)wz;
    if (fabsf(z) < 1e-8f) z = 1e-8f;
    wout[cell] = make_float2((float)wx / z, (float)wy / z);
  }
}

__device__ inline bool decode_slot(int slot, const int* ivl, int& n, int& b, int& iv) {
  int ivi = slot / (NMAX * BB);
  int rem = slot % (NMAX * BB);
  n = rem / BB; b = rem % BB;
  iv = ivl[ivi];
  return n < TC - iv;
}

// 2-term bf16-split MFMA: S_tile = Ah*Bh + Ah*Bl + Al*Bh
__device__ inline float4v s_tile(short8v ah, short8v al, short8v bh, short8v bl) {
  float4v acc = {0.f, 0.f, 0.f, 0.f};
  acc = __builtin_amdgcn_mfma_f32_16x16x32_bf16(ah, bh, acc, 0, 0, 0);
  acc = __builtin_amdgcn_mfma_f32_16x16x32_bf16(ah, bl, acc, 0, 0, 0);
  acc = __builtin_amdgcn_mfma_f32_16x16x32_bf16(al, bh, acc, 0, 0, 0);
  return acc;
}

// ------------------------------------------------------------------
// K3: inverse row norms. wave = 16 rows; double-buffered B loads.
// (round-3 version — measured faster, no spill: light loop state)
// ------------------------------------------------------------------
__global__ void __launch_bounds__(256) k_rnorm(const short8v* __restrict__ dsp,
                                               const int* __restrict__ ivl,
                                               float* __restrict__ irn) {
  int slot = blockIdx.x;
  int n, b, iv;
  if (!decode_slot(slot, ivl, n, b, iv)) return;
  int wid = threadIdx.x >> 6, lane = threadIdx.x & 63;
  int rowtile = blockIdx.y * 4 + wid;
  if (rowtile >= RT) return;
  int q = lane >> 4, li = lane & 15;
  const short8v* D0 = dsp + (size_t)(n * BB + b) * 8 * MM;
  const short8v* B0 = dsp + (size_t)((n + iv) * BB + b) * 8 * MM + (size_t)q * MM + li;
  const short8v* B4 = B0 + 4 * MM;
  int row16 = rowtile * 16;
  short8v ah = D0[(size_t)q * MM + row16 + li];
  short8v al = D0[(size_t)(q + 4) * MM + row16 + li];
  short8v bh = B0[0], bl = B4[0];
  float4v racc = {0.f, 0.f, 0.f, 0.f};
#pragma unroll 3
  for (int jt = 0; jt < JT - 1; ++jt) {
    short8v bhn = B0[(jt + 1) * 16];
    short8v bln = B4[(jt + 1) * 16];
    float4v acc = s_tile(ah, al, bh, bl);
#pragma unroll
    for (int r = 0; r < 4; ++r) { float t = fmaxf(acc[r], 0.f); racc[r] = fmaf(t, t, racc[r]); }
    bh = bhn; bl = bln;
  }
  {
    float4v acc = s_tile(ah, al, bh, bl);
#pragma unroll
    for (int r = 0; r < 4; ++r) { float t = fmaxf(acc[r], 0.f); racc[r] = fmaf(t, t, racc[r]); }
  }
#pragma unroll
  for (int m = 1; m <= 8; m <<= 1)
#pragma unroll
    for (int r = 0; r < 4; ++r) racc[r] += __shfl_xor(racc[r], m);
  if (li == 0) {
#pragma unroll
    for (int r = 0; r < 4; ++r)
      irn[(size_t)slot * MM + row16 + q * 4 + r] = 1.f / fmaxf(sqrtf(racc[r]), EPSF);
  }
}

// ------------------------------------------------------------------
// K4: inverse col norms of (relu(S)/rnorm_i). wave = 16 cols (j).
// (round-3 prefetch version)
// ------------------------------------------------------------------
__global__ void __launch_bounds__(256) k_cnorm(const short8v* __restrict__ dsp,
                                               const int* __restrict__ ivl,
                                               const float* __restrict__ irn,
                                               float* __restrict__ icn) {
  int slot = blockIdx.x;
  int n, b, iv;
  if (!decode_slot(slot, ivl, n, b, iv)) return;
  int wid = threadIdx.x >> 6, lane = threadIdx.x & 63;
  int coltile = blockIdx.y * 4 + wid;
  if (coltile >= RT) return;
  int q = lane >> 4, li = lane & 15;
  const short8v* D1 = dsp + (size_t)((n + iv) * BB + b) * 8 * MM;
  const short8v* B0 = dsp + (size_t)(n * BB + b) * 8 * MM + (size_t)q * MM + li;
  const short8v* B4 = B0 + 4 * MM;
  int col16 = coltile * 16;
  short8v ah = D1[(size_t)q * MM + col16 + li];
  short8v al = D1[(size_t)(q + 4) * MM + col16 + li];
  const float* irnS = irn + (size_t)slot * MM + li;
  short8v bh = B0[0], bl = B4[0];
  float ir = irnS[0];
  float4v cacc = {0.f, 0.f, 0.f, 0.f};
#pragma unroll 3
  for (int it = 0; it < JT - 1; ++it) {
    short8v bhn = B0[(it + 1) * 16];
    short8v bln = B4[(it + 1) * 16];
    float irn_ = irnS[(it + 1) * 16];
    float4v acc = s_tile(ah, al, bh, bl);
#pragma unroll
    for (int r = 0; r < 4; ++r) { float t = fmaxf(acc[r], 0.f) * ir; cacc[r] = fmaf(t, t, cacc[r]); }
    bh = bhn; bl = bln; ir = irn_;
  }
  {
    float4v acc = s_tile(ah, al, bh, bl);
#pragma unroll
    for (int r = 0; r < 4; ++r) { float t = fmaxf(acc[r], 0.f) * ir; cacc[r] = fmaf(t, t, cacc[r]); }
  }
#pragma unroll
  for (int m = 1; m <= 8; m <<= 1)
#pragma unroll
    for (int r = 0; r < 4; ++r) cacc[r] += __shfl_xor(cacc[r], m);
  if (li == 0) {
#pragma unroll
    for (int r = 0; r < 4; ++r)
      icn[(size_t)slot * MM + col16 + q * 4 + r] = 1.f / fmaxf(sqrtf(cacc[r]), EPSF);
  }
}

// ------------------------------------------------------------------
// K5: loss. ROUND-2 loop structure (loads at loop top, no manual
// prefetch — the r3 prefetch spilled to 256 VGPRs) + ctab coord table
// + expanded-distance mask + merged hinge select.
// ------------------------------------------------------------------
__global__ void __launch_bounds__(256) k_loss(const short8v* __restrict__ dsp,
                                              const int* __restrict__ ivl,
                                              const float* __restrict__ irn,
                                              const float* __restrict__ icn,
                                              const float2* __restrict__ warped,
                                              const float4* __restrict__ ctab,
                                              double* __restrict__ partials) {
  int slot = blockIdx.x;
  int wid = threadIdx.x >> 6, lane = threadIdx.x & 63;
  int rowtile = blockIdx.y * 4 + wid;
  int n, b, iv;
  bool valid = decode_slot(slot, ivl, n, b, iv);
  if (!valid) {
    if (rowtile < RT && lane == 0) partials[(size_t)slot * RT + rowtile] = 0.0;
    return;
  }
  if (rowtile >= RT) return;
  int q = lane >> 4, li = lane & 15;
  const short8v* D0 = dsp + (size_t)(n * BB + b) * 8 * MM;
  const short8v* B0 = dsp + (size_t)((n + iv) * BB + b) * 8 * MM + (size_t)q * MM + li;
  const short8v* B4 = B0 + 4 * MM;
  int row16 = rowtile * 16;
  short8v ah = D0[(size_t)q * MM + row16 + li];
  short8v al = D0[(size_t)(q + 4) * MM + row16 + li];
  float irn4[4], wxm[4], wym[4], Qr[4];
#pragma unroll
  for (int r = 0; r < 4; ++r) {
    int row = row16 + q * 4 + r;
    irn4[r] = irn[(size_t)slot * MM + row];
    float2 wp = warped[(size_t)slot * MM + row];
    wxm[r] = -2.f * wp.x;
    wym[r] = -2.f * wp.y;
    Qr[r]  = fmaf(-wp.x, wp.x, fmaf(-wp.y, wp.y, 56.25f));
  }
  const float*  icnS = icn + (size_t)slot * MM + li;
  const float4* ctS  = ctab + li;
  float lacc = 0.f;
#pragma unroll 3
  for (int jt = 0; jt < JT; ++jt) {
    int o = jt * 16;
    short8v bh = B0[o];
    short8v bl = B4[o];
    float ic = icnS[o];
    float4 ct = ctS[o];
    float4v acc = s_tile(ah, al, bh, bl);
#pragma unroll
    for (int r = 0; r < 4; ++r) {
      float s  = fmaxf(acc[r], 0.f);
      float Dv = s * ic * irn4[r];
      float pm = fmaf(Dv, -0.05f, 0.05f);
      float nm = Dv - 0.2f;
      float t2 = fmaf(ct.y, wym[r], fmaf(ct.x, wxm[r], ct.z));
      float c  = (t2 <= Qr[r]) ? pm : nm;
      lacc += fmaxf(c, 0.f);
    }
  }
#pragma unroll
  for (int off = 32; off > 0; off >>= 1) lacc += __shfl_xor(lacc, off);
  if (lane == 0) partials[(size_t)slot * RT + rowtile] = (double)lacc;
}

// ------------------------------------------------------------------
// K6: final reduction
// ------------------------------------------------------------------
__global__ void k_final(const double* __restrict__ partials, const int* __restrict__ ivl,
                        int niv, float* __restrict__ out) {
  int lane = threadIdx.x; // 64 threads
  double total = 0.0;
  for (int ivi = 0; ivi < niv; ++ivi) {
    double local = 0.0;
    int base = ivi * NMAX * BB * RT;
    for (int p = lane; p < NMAX * BB * RT; p += 64) local += partials[base + p];
    for (int off = 32; off > 0; off >>= 1) local += __shfl_down(local, off);
    int N = TC - ivl[ivi];
    total += local / ((double)N * BB * (double)MM * (double)MM);
  }
  if (lane == 0) out[0] = (float)(total / (double)niv);
}

// ------------------------------------------------------------------
extern "C" void kernel_launch(void* const* d_in, const int* in_sizes, int n_in,
                              void* d_out, int out_size, void* d_ws, size_t ws_size,
                              hipStream_t stream) {
  const float* pred = (const float*)d_in[0];
  const float* rv   = (const float*)d_in[1];
  const float* tv   = (const float*)d_in[2];
  const float* nts  = (const float*)d_in[3];
  const float* dep  = (const float*)d_in[4];
  const float* Ks   = (const float*)d_in[5];
  const float* Kin  = (const float*)d_in[6];
  const float* osz  = (const float*)d_in[7];
  const int*   ivl  = (const int*)d_in[8];
  int niv = in_sizes[8];
  int slots = niv * NMAX * BB;

  char* ws = (char*)d_ws;
  size_t off = 0;
  short8v* dsp = (short8v*)(ws + off); off += (size_t)TC * BB * 8 * MM * 16;
  float2* warped = (float2*)(ws + off); off += (size_t)slots * MM * 8;
  float* irn = (float*)(ws + off);     off += (size_t)slots * MM * 4;
  float* icn = (float*)(ws + off);     off += (size_t)slots * MM * 4;
  off = (off + 255) & ~(size_t)255;
  double* partials = (double*)(ws + off); off += (size_t)slots * RT * 8;
  float4* ctab = (float4*)(ws + off);  off += (size_t)MM * 16;

  hipLaunchKernelGGL(k_split, dim3(TC * BB + 1, 5), dim3(256), 0, stream, pred, dsp, ctab);
  hipLaunchKernelGGL(k_warp, dim3(slots), dim3(64), 0, stream,
                     rv, tv, nts, dep, Ks, Kin, osz, ivl, warped);
  dim3 grid(slots, (RT + 3) / 4);
  hipLaunchKernelGGL(k_rnorm, grid, dim3(256), 0, stream, dsp, ivl, irn);
  hipLaunchKernelGGL(k_cnorm, grid, dim3(256), 0, stream, dsp, ivl, irn, icn);
  hipLaunchKernelGGL(k_loss, grid, dim3(256), 0, stream,
                     dsp, ivl, irn, icn, warped, ctab, partials);
  hipLaunchKernelGGL(k_final, dim3(1), dim3(64), 0, stream, partials, ivl, niv, (float*)d_out);
}

// Round 5
// 116.478 us; speedup vs baseline: 3.7685x; 1.3400x over previous
//
#include <hip/hip_runtime.h>
#include <math.h>

// ---- problem constants ----
#define TT   5
#define CAM  4
#define TC   20
#define BB   2
#define CF   32
#define HC   30
#define WC   40
#define MM   1200
#define NMAX 19
#define EPSF 1e-12f
#define JT   75      // 16-col tiles per item
#define RG   38      // row-groups of 32 rows per slot (ceil(1200/32))
#define CT   5       // corr-kernel tiles of 256 rows

typedef __attribute__((ext_vector_type(8))) short short8v;   // 8 bf16 (4 VGPR)
typedef __attribute__((ext_vector_type(4))) float float4v;

__device__ inline unsigned short f2bf(float x) {
  unsigned int u = __float_as_uint(x);
  unsigned int r = (u + 0x7FFFu + ((u >> 16) & 1u)) >> 16;  // RNE
  return (unsigned short)r;
}
__device__ inline float bf2f(unsigned short h) {
  return __uint_as_float(((unsigned int)h) << 16);
}

// ------------------------------------------------------------------
// K1: channel-L2-normalize, split into bf16 hi/lo, store MFMA-ready:
// dsp[tcb][sec][pix] (16B each), sec = (hilo ? 4 : 0) + kquarter.
// ------------------------------------------------------------------
__global__ void k_split(const float* __restrict__ pred, short8v* __restrict__ dsp) {
  int tb = blockIdx.x;
  int tid = threadIdx.x;
  const float* src = pred + (size_t)tb * CF * MM;
  short8v*     dst = dsp  + (size_t)tb * 8 * MM;
  int pix = blockIdx.y * 240 + tid;
  if (tid >= 240 || pix >= MM) return;
  float v[CF]; float ss = 0.f;
#pragma unroll
  for (int c = 0; c < CF; ++c) { float x = src[c * MM + pix]; v[c] = x; ss = fmaf(x, x, ss); }
  float inv = 1.f / fmaxf(sqrtf(ss), EPSF);
  unsigned short hi[CF], lo[CF];
#pragma unroll
  for (int c = 0; c < CF; ++c) {
    float xn = v[c] * inv;
    unsigned short h = f2bf(xn);
    hi[c] = h;
    lo[c] = f2bf(xn - bf2f(h));
  }
#pragma unroll
  for (int s = 0; s < 4; ++s) {
    short8v oh, ol;
#pragma unroll
    for (int e = 0; e < 8; ++e) { oh[e] = (short)hi[s*8+e]; ol[e] = (short)lo[s*8+e]; }
    dst[(size_t)s * MM + pix]       = oh;
    dst[(size_t)(4 + s) * MM + pix] = ol;
  }
}

// ------------------------------------------------------------------
// K2: homography (f64) + warped coords per (iv,n,b)
// ------------------------------------------------------------------
__device__ inline void rodrigues_d(const double rv[3], double R[9]) {
  double th = sqrt(rv[0]*rv[0] + rv[1]*rv[1] + rv[2]*rv[2]);
  double thc = fmax(th, 1e-12);
  double kx = rv[0] / thc, ky = rv[1] / thc, kz = rv[2] / thc;
  double st = sin(th), ct = cos(th);
  double Km[9] = { 0.0, -kz,  ky,  kz, 0.0, -kx,  -ky, kx, 0.0 };
  double K2[9];
  for (int r = 0; r < 3; ++r)
    for (int c = 0; c < 3; ++c)
      K2[r*3+c] = Km[r*3+0]*Km[0*3+c] + Km[r*3+1]*Km[1*3+c] + Km[r*3+2]*Km[2*3+c];
  for (int r = 0; r < 3; ++r)
    for (int c = 0; c < 3; ++c)
      R[r*3+c] = (r == c ? 1.0 : 0.0) + st * Km[r*3+c] + (1.0 - ct) * K2[r*3+c];
}
__device__ inline void mm3(const double* A, const double* B, double* C) {
  for (int r = 0; r < 3; ++r)
    for (int c = 0; c < 3; ++c)
      C[r*3+c] = A[r*3+0]*B[0*3+c] + A[r*3+1]*B[1*3+c] + A[r*3+2]*B[2*3+c];
}

__global__ void k_warp(const float* __restrict__ rv_, const float* __restrict__ tv_,
                       const float* __restrict__ nts_, const float* __restrict__ dep_,
                       const float* __restrict__ Ks_, const float* __restrict__ Kin_,
                       const float* __restrict__ osz_, const int* __restrict__ ivl,
                       float2* __restrict__ warped) {
  int slot = blockIdx.x;
  int ivi = slot / (NMAX * BB);
  int rem = slot % (NMAX * BB);
  int n = rem / BB, b = rem % BB;
  int iv = ivl[ivi];
  if (n >= TC - iv) return;
  int q0 = n, q1 = n + iv;
  int t0 = q0 / CAM, c0 = q0 % CAM;
  int t1 = q1 / CAM, c1 = q1 % CAM;
  size_t e0 = (size_t)(t0 * BB + b) * CAM + c0;
  size_t e1 = (size_t)(t1 * BB + b) * CAM + c1;

  double rv0[3], tv0[3], rv1[3], tv1[3], nv[3];
  for (int k = 0; k < 3; ++k) {
    rv0[k] = rv_[e0*3 + k]; tv0[k] = tv_[e0*3 + k];
    rv1[k] = rv_[e1*3 + k]; tv1[k] = tv_[e1*3 + k];
    nv[k]  = nts_[e0*3 + k];
  }
  double d = dep_[e0];
  double K9[9], Ki9[9];
  for (int k = 0; k < 9; ++k) { K9[k] = Ks_[e0*9 + k]; Ki9[k] = Kin_[e0*9 + k]; }

  double R0[9], R1[9], R[9];
  rodrigues_d(rv0, R0);
  rodrigues_d(rv1, R1);
  for (int r = 0; r < 3; ++r)
    for (int c = 0; c < 3; ++c)
      R[r*3+c] = R1[r*3+0]*R0[c*3+0] + R1[r*3+1]*R0[c*3+1] + R1[r*3+2]*R0[c*3+2];
  double tvec[3];
  for (int r = 0; r < 3; ++r)
    tvec[r] = tv1[r] - (R[r*3+0]*tv0[0] + R[r*3+1]*tv0[1] + R[r*3+2]*tv0[2]);
  double Mid[9];
  for (int r = 0; r < 3; ++r)
    for (int c = 0; c < 3; ++c)
      Mid[r*3+c] = R[r*3+c] - tvec[r] * nv[c] / d;
  double T1[9], Hm[9];
  mm3(K9, Mid, T1);
  mm3(T1, Ki9, Hm);

  double osz0 = osz_[e0*2 + 0], osz1 = osz_[e0*2 + 1];
  double s0 = 240.0 / osz0, s1 = 320.0 / osz1;
  double sv[3] = { s1, s0, 1.0 };
  double Hs[9];
  for (int r = 0; r < 3; ++r)
    for (int c = 0; c < 3; ++c)
      Hs[r*3+c] = Hm[r*3+c] * sv[r] / sv[c];

  float2* wout = warped + (size_t)slot * MM;
  for (int cell = threadIdx.x; cell < MM; cell += blockDim.x) {
    double x = (double)((cell % WC) * 8);
    double y = (double)((cell / WC) * 8);
    double wx = Hs[0]*x + Hs[1]*y + Hs[2];
    double wy = Hs[3]*x + Hs[4]*y + Hs[5];
    double wz = Hs[6]*x + Hs[7]*y + Hs[8];
    float z = (float)wz;
    if (fabsf(z) < 1e-8f) z = 1e-8f;
    wout[cell] = make_float2((float)wx / z, (float)wy / z);
  }
}

__device__ inline bool decode_slot(int slot, const int* ivl, int& n, int& b, int& iv) {
  int ivi = slot / (NMAX * BB);
  int rem = slot % (NMAX * BB);
  n = rem / BB; b = rem % BB;
  iv = ivl[ivi];
  return n < TC - iv;
}

// 2-term bf16-split MFMA: S_tile = Ah*Bh + Ah*Bl + Al*Bh
__device__ inline float4v s_tile(short8v ah, short8v al, short8v bh, short8v bl) {
  float4v acc = {0.f, 0.f, 0.f, 0.f};
  acc = __builtin_amdgcn_mfma_f32_16x16x32_bf16(ah, bh, acc, 0, 0, 0);
  acc = __builtin_amdgcn_mfma_f32_16x16x32_bf16(ah, bl, acc, 0, 0, 0);
  acc = __builtin_amdgcn_mfma_f32_16x16x32_bf16(al, bh, acc, 0, 0, 0);
  return acc;
}

// ------------------------------------------------------------------
// K3: inverse row norms. 1 wave/block; wave owns 32 rows (2 tiles);
// B-fragments reused for both tiles; prefetched.
// C/D layout: col = lane&15, row = (lane>>4)*4 + reg.
// ------------------------------------------------------------------
__global__ void __launch_bounds__(64) k_rnorm(const short8v* __restrict__ dsp,
                                              const int* __restrict__ ivl,
                                              float* __restrict__ irn) {
  int slot = blockIdx.x;
  int n, b, iv;
  if (!decode_slot(slot, ivl, n, b, iv)) return;
  int rg = blockIdx.y;
  int lane = threadIdx.x & 63, q = lane >> 4, li = lane & 15;
  int base = rg * 32;
  bool v1 = (base + 16) < MM;
  int r16a = base, r16b = v1 ? base + 16 : base;
  const short8v* D0 = dsp + (size_t)(n * BB + b) * 8 * MM;
  const short8v* B0 = dsp + (size_t)((n + iv) * BB + b) * 8 * MM + (size_t)q * MM + li;
  const short8v* B4 = B0 + 4 * MM;
  short8v ah0 = D0[(size_t)q * MM + r16a + li];
  short8v al0 = D0[(size_t)(q + 4) * MM + r16a + li];
  short8v ah1 = D0[(size_t)q * MM + r16b + li];
  short8v al1 = D0[(size_t)(q + 4) * MM + r16b + li];
  short8v bh = B0[0], bl = B4[0];
  float4v racc0 = {0.f, 0.f, 0.f, 0.f};
  float4v racc1 = {0.f, 0.f, 0.f, 0.f};
#pragma unroll 3
  for (int jt = 0; jt < JT - 1; ++jt) {
    short8v bhn = B0[(jt + 1) * 16];
    short8v bln = B4[(jt + 1) * 16];
    float4v acc0 = s_tile(ah0, al0, bh, bl);
    float4v acc1 = s_tile(ah1, al1, bh, bl);
#pragma unroll
    for (int r = 0; r < 4; ++r) {
      float t0 = fmaxf(acc0[r], 0.f); racc0[r] = fmaf(t0, t0, racc0[r]);
      float t1 = fmaxf(acc1[r], 0.f); racc1[r] = fmaf(t1, t1, racc1[r]);
    }
    bh = bhn; bl = bln;
  }
  {
    float4v acc0 = s_tile(ah0, al0, bh, bl);
    float4v acc1 = s_tile(ah1, al1, bh, bl);
#pragma unroll
    for (int r = 0; r < 4; ++r) {
      float t0 = fmaxf(acc0[r], 0.f); racc0[r] = fmaf(t0, t0, racc0[r]);
      float t1 = fmaxf(acc1[r], 0.f); racc1[r] = fmaf(t1, t1, racc1[r]);
    }
  }
#pragma unroll
  for (int m = 1; m <= 8; m <<= 1)
#pragma unroll
    for (int r = 0; r < 4; ++r) {
      racc0[r] += __shfl_xor(racc0[r], m);
      racc1[r] += __shfl_xor(racc1[r], m);
    }
  if (li == 0) {
#pragma unroll
    for (int r = 0; r < 4; ++r)
      irn[(size_t)slot * MM + r16a + q * 4 + r] = 1.f / fmaxf(sqrtf(racc0[r]), EPSF);
    if (v1) {
#pragma unroll
      for (int r = 0; r < 4; ++r)
        irn[(size_t)slot * MM + r16b + q * 4 + r] = 1.f / fmaxf(sqrtf(racc1[r]), EPSF);
    }
  }
}

// ------------------------------------------------------------------
// K4: inverse col norms of (relu(S)·irn_i). wave owns 32 cols (2 tiles).
// ------------------------------------------------------------------
__global__ void __launch_bounds__(64) k_cnorm(const short8v* __restrict__ dsp,
                                              const int* __restrict__ ivl,
                                              const float* __restrict__ irn,
                                              float* __restrict__ icn) {
  int slot = blockIdx.x;
  int n, b, iv;
  if (!decode_slot(slot, ivl, n, b, iv)) return;
  int rg = blockIdx.y;
  int lane = threadIdx.x & 63, q = lane >> 4, li = lane & 15;
  int base = rg * 32;
  bool v1 = (base + 16) < MM;
  int c16a = base, c16b = v1 ? base + 16 : base;
  const short8v* D1 = dsp + (size_t)((n + iv) * BB + b) * 8 * MM;
  const short8v* B0 = dsp + (size_t)(n * BB + b) * 8 * MM + (size_t)q * MM + li;
  const short8v* B4 = B0 + 4 * MM;
  short8v ah0 = D1[(size_t)q * MM + c16a + li];
  short8v al0 = D1[(size_t)(q + 4) * MM + c16a + li];
  short8v ah1 = D1[(size_t)q * MM + c16b + li];
  short8v al1 = D1[(size_t)(q + 4) * MM + c16b + li];
  const float* irnS = irn + (size_t)slot * MM + li;
  short8v bh = B0[0], bl = B4[0];
  float ir = irnS[0];
  float4v cacc0 = {0.f, 0.f, 0.f, 0.f};
  float4v cacc1 = {0.f, 0.f, 0.f, 0.f};
#pragma unroll 3
  for (int it = 0; it < JT - 1; ++it) {
    short8v bhn = B0[(it + 1) * 16];
    short8v bln = B4[(it + 1) * 16];
    float irn_ = irnS[(it + 1) * 16];
    float4v acc0 = s_tile(ah0, al0, bh, bl);
    float4v acc1 = s_tile(ah1, al1, bh, bl);
#pragma unroll
    for (int r = 0; r < 4; ++r) {
      float t0 = fmaxf(acc0[r], 0.f) * ir; cacc0[r] = fmaf(t0, t0, cacc0[r]);
      float t1 = fmaxf(acc1[r], 0.f) * ir; cacc1[r] = fmaf(t1, t1, cacc1[r]);
    }
    bh = bhn; bl = bln; ir = irn_;
  }
  {
    float4v acc0 = s_tile(ah0, al0, bh, bl);
    float4v acc1 = s_tile(ah1, al1, bh, bl);
#pragma unroll
    for (int r = 0; r < 4; ++r) {
      float t0 = fmaxf(acc0[r], 0.f) * ir; cacc0[r] = fmaf(t0, t0, cacc0[r]);
      float t1 = fmaxf(acc1[r], 0.f) * ir; cacc1[r] = fmaf(t1, t1, cacc1[r]);
    }
  }
#pragma unroll
  for (int m = 1; m <= 8; m <<= 1)
#pragma unroll
    for (int r = 0; r < 4; ++r) {
      cacc0[r] += __shfl_xor(cacc0[r], m);
      cacc1[r] += __shfl_xor(cacc1[r], m);
    }
  if (li == 0) {
#pragma unroll
    for (int r = 0; r < 4; ++r)
      icn[(size_t)slot * MM + c16a + q * 4 + r] = 1.f / fmaxf(sqrtf(cacc0[r]), EPSF);
    if (v1) {
#pragma unroll
      for (int r = 0; r < 4; ++r)
        icn[(size_t)slot * MM + c16b + q * 4 + r] = 1.f / fmaxf(sqrtf(cacc1[r]), EPSF);
    }
  }
}

// ------------------------------------------------------------------
// K5: loss, mask-free hot loop: lacc += relu(fma(acc, ic*irn, -0.2)).
// Masked cells handled exactly by k_corr. Wave owns 32 rows (2 tiles).
// ------------------------------------------------------------------
__global__ void __launch_bounds__(64) k_loss(const short8v* __restrict__ dsp,
                                             const int* __restrict__ ivl,
                                             const float* __restrict__ irn,
                                             const float* __restrict__ icn,
                                             double* __restrict__ partials) {
  int slot = blockIdx.x, rg = blockIdx.y;
  int lane = threadIdx.x & 63;
  int n, b, iv;
  if (!decode_slot(slot, ivl, n, b, iv)) {
    if (lane == 0) partials[(size_t)slot * RG + rg] = 0.0;
    return;
  }
  int q = lane >> 4, li = lane & 15;
  int base = rg * 32;
  bool v1 = (base + 16) < MM;
  int r16a = base, r16b = v1 ? base + 16 : base;
  const short8v* D0 = dsp + (size_t)(n * BB + b) * 8 * MM;
  const short8v* B0 = dsp + (size_t)((n + iv) * BB + b) * 8 * MM + (size_t)q * MM + li;
  const short8v* B4 = B0 + 4 * MM;
  short8v ah0 = D0[(size_t)q * MM + r16a + li];
  short8v al0 = D0[(size_t)(q + 4) * MM + r16a + li];
  short8v ah1 = D0[(size_t)q * MM + r16b + li];
  short8v al1 = D0[(size_t)(q + 4) * MM + r16b + li];
  float uA[4], uB[4];
#pragma unroll
  for (int r = 0; r < 4; ++r) {
    uA[r] = irn[(size_t)slot * MM + r16a + q * 4 + r];
    uB[r] = v1 ? irn[(size_t)slot * MM + r16b + q * 4 + r] : 0.f;
  }
  const float* icnS = icn + (size_t)slot * MM + li;
  float lacc = 0.f;
#pragma unroll 3
  for (int jt = 0; jt < JT; ++jt) {
    int o = jt * 16;
    short8v bh = B0[o];
    short8v bl = B4[o];
    float ic = icnS[o];
    float4v acc0 = s_tile(ah0, al0, bh, bl);
    float4v acc1 = s_tile(ah1, al1, bh, bl);
#pragma unroll
    for (int r = 0; r < 4; ++r) {
      lacc += fmaxf(fmaf(acc0[r], ic * uA[r], -0.2f), 0.f);
      lacc += fmaxf(fmaf(acc1[r], ic * uB[r], -0.2f), 0.f);
    }
  }
#pragma unroll
  for (int off = 32; off > 0; off >>= 1) lacc += __shfl_xor(lacc, off);
  if (lane == 0) partials[(size_t)slot * RG + rg] = (double)lacc;
}

// ------------------------------------------------------------------
// K5b: correction for masked cells (<=4 per row):
//   corr = 0.05*relu(1-D) - relu(D-0.2)  summed over cells with
//   (cx-wx)^2+(cy-wy)^2 <= 56.25. One thread per row.
// ------------------------------------------------------------------
__global__ void __launch_bounds__(256) k_corr(const short8v* __restrict__ dsp,
                                              const int* __restrict__ ivl,
                                              const float* __restrict__ irn,
                                              const float* __restrict__ icn,
                                              const float2* __restrict__ warped,
                                              double* __restrict__ partials2) {
  __shared__ double swsum[4];
  int slot = blockIdx.x, tile = blockIdx.y;
  int t = threadIdx.x;
  int n, b, iv;
  bool valid = decode_slot(slot, ivl, n, b, iv);
  double corr = 0.0;
  int row = tile * 256 + t;
  if (valid && row < MM) {
    float2 wp = warped[(size_t)slot * MM + row];
    int kx0 = max(0, (int)ceilf((wp.x - 7.5f) * 0.125f));
    int kx1 = min(WC - 1, (int)floorf((wp.x + 7.5f) * 0.125f));
    int ky0 = max(0, (int)ceilf((wp.y - 7.5f) * 0.125f));
    int ky1 = min(HC - 1, (int)floorf((wp.y + 7.5f) * 0.125f));
    if (kx0 <= kx1 && ky0 <= ky1) {
      const short8v* D0 = dsp + (size_t)(n * BB + b) * 8 * MM;
      const short8v* D1 = dsp + (size_t)((n + iv) * BB + b) * 8 * MM;
      float a[CF];
#pragma unroll
      for (int qq = 0; qq < 4; ++qq) {
        short8v h = D0[(size_t)qq * MM + row];
        short8v l = D0[(size_t)(4 + qq) * MM + row];
#pragma unroll
        for (int e = 0; e < 8; ++e)
          a[qq * 8 + e] = bf2f((unsigned short)h[e]) + bf2f((unsigned short)l[e]);
      }
      float ir = irn[(size_t)slot * MM + row];
      float fcorr = 0.f;
      for (int ky = ky0; ky <= ky1; ++ky) {
        for (int kx = kx0; kx <= kx1; ++kx) {
          float dx = (float)(kx * 8) - wp.x;
          float dy = (float)(ky * 8) - wp.y;
          if (fmaf(dx, dx, dy * dy) <= 56.25f) {
            int j = ky * WC + kx;
            float dot = 0.f;
#pragma unroll
            for (int qq = 0; qq < 4; ++qq) {
              short8v h1 = D1[(size_t)qq * MM + j];
              short8v l1 = D1[(size_t)(4 + qq) * MM + j];
#pragma unroll
              for (int e = 0; e < 8; ++e)
                dot = fmaf(a[qq * 8 + e],
                           bf2f((unsigned short)h1[e]) + bf2f((unsigned short)l1[e]), dot);
            }
            float s = fmaxf(dot, 0.f);
            float D = s * ir * icn[(size_t)slot * MM + j];
            fcorr += 0.05f * fmaxf(1.f - D, 0.f) - fmaxf(D - 0.2f, 0.f);
          }
        }
      }
      corr = (double)fcorr;
    }
  }
#pragma unroll
  for (int off = 32; off > 0; off >>= 1) corr += __shfl_down(corr, off);
  int wid = t >> 6, lane = t & 63;
  if (lane == 0) swsum[wid] = corr;
  __syncthreads();
  if (t == 0) partials2[(size_t)slot * CT + tile] = swsum[0] + swsum[1] + swsum[2] + swsum[3];
}

// ------------------------------------------------------------------
// K6: final reduction
// ------------------------------------------------------------------
__global__ void k_final(const double* __restrict__ partials,
                        const double* __restrict__ partials2,
                        const int* __restrict__ ivl,
                        int niv, float* __restrict__ out) {
  int lane = threadIdx.x; // 64 threads
  double total = 0.0;
  for (int ivi = 0; ivi < niv; ++ivi) {
    double local = 0.0;
    int base1 = ivi * NMAX * BB * RG;
    for (int p = lane; p < NMAX * BB * RG; p += 64) local += partials[base1 + p];
    int base2 = ivi * NMAX * BB * CT;
    for (int p = lane; p < NMAX * BB * CT; p += 64) local += partials2[base2 + p];
    for (int off = 32; off > 0; off >>= 1) local += __shfl_down(local, off);
    int N = TC - ivl[ivi];
    total += local / ((double)N * BB * (double)MM * (double)MM);
  }
  if (lane == 0) out[0] = (float)(total / (double)niv);
}

// ------------------------------------------------------------------
extern "C" void kernel_launch(void* const* d_in, const int* in_sizes, int n_in,
                              void* d_out, int out_size, void* d_ws, size_t ws_size,
                              hipStream_t stream) {
  const float* pred = (const float*)d_in[0];
  const float* rv   = (const float*)d_in[1];
  const float* tv   = (const float*)d_in[2];
  const float* nts  = (const float*)d_in[3];
  const float* dep  = (const float*)d_in[4];
  const float* Ks   = (const float*)d_in[5];
  const float* Kin  = (const float*)d_in[6];
  const float* osz  = (const float*)d_in[7];
  const int*   ivl  = (const int*)d_in[8];
  int niv = in_sizes[8];
  int slots = niv * NMAX * BB;

  char* ws = (char*)d_ws;
  size_t off = 0;
  short8v* dsp = (short8v*)(ws + off); off += (size_t)TC * BB * 8 * MM * 16;
  float2* warped = (float2*)(ws + off); off += (size_t)slots * MM * 8;
  float* irn = (float*)(ws + off);     off += (size_t)slots * MM * 4;
  float* icn = (float*)(ws + off);     off += (size_t)slots * MM * 4;
  off = (off + 255) & ~(size_t)255;
  double* partials = (double*)(ws + off);  off += (size_t)slots * RG * 8;
  double* partials2 = (double*)(ws + off); off += (size_t)slots * CT * 8;

  hipLaunchKernelGGL(k_split, dim3(TC * BB, 5), dim3(256), 0, stream, pred, dsp);
  hipLaunchKernelGGL(k_warp, dim3(slots), dim3(64), 0, stream,
                     rv, tv, nts, dep, Ks, Kin, osz, ivl, warped);
  dim3 sgrid(slots, RG);
  hipLaunchKernelGGL(k_rnorm, sgrid, dim3(64), 0, stream, dsp, ivl, irn);
  hipLaunchKernelGGL(k_cnorm, sgrid, dim3(64), 0, stream, dsp, ivl, irn, icn);
  hipLaunchKernelGGL(k_loss, sgrid, dim3(64), 0, stream, dsp, ivl, irn, icn, partials);
  hipLaunchKernelGGL(k_corr, dim3(slots, CT), dim3(256), 0, stream,
                     dsp, ivl, irn, icn, warped, partials2);
  hipLaunchKernelGGL(k_final, dim3(1), dim3(64), 0, stream,
                     partials, partials2, ivl, niv, (float*)d_out);
}

// Round 6
// 105.825 us; speedup vs baseline: 4.1478x; 1.1007x over previous
//
#include <hip/hip_runtime.h>
#include <math.h>

// ---- problem constants ----
#define TT   5
#define CAM  4
#define TC   20
#define BB   2
#define CF   32
#define HC   30
#define WC   40
#define MM   1200
#define NMAX 19
#define EPSF 1e-12f
#define JT   75      // 16-col tiles per item
#define RG   38      // row-groups of 32 rows per slot (ceil(1200/32))
#define JSP  2       // j-loop split factor
#define CT   5       // corr-kernel tiles of 256 rows

typedef __attribute__((ext_vector_type(8))) short short8v;   // 8 bf16 (4 VGPR)
typedef __attribute__((ext_vector_type(4))) float float4v;

__device__ inline unsigned short f2bf(float x) {
  unsigned int u = __float_as_uint(x);
  unsigned int r = (u + 0x7FFFu + ((u >> 16) & 1u)) >> 16;  // RNE
  return (unsigned short)r;
}
__device__ inline float bf2f(unsigned short h) {
  return __uint_as_float(((unsigned int)h) << 16);
}

// ------------------------------------------------------------------
// K1: channel-L2-normalize, round to bf16 (hi only), store MFMA-ready:
// dsp[tcb][sec][pix] (16B each), sec = kquarter (channels q*8..q*8+7).
// ------------------------------------------------------------------
__global__ void k_split(const float* __restrict__ pred, short8v* __restrict__ dsp) {
  int tb = blockIdx.x;
  int tid = threadIdx.x;
  const float* src = pred + (size_t)tb * CF * MM;
  short8v*     dst = dsp  + (size_t)tb * 4 * MM;
  int pix = blockIdx.y * 240 + tid;
  if (tid >= 240 || pix >= MM) return;
  float v[CF]; float ss = 0.f;
#pragma unroll
  for (int c = 0; c < CF; ++c) { float x = src[c * MM + pix]; v[c] = x; ss = fmaf(x, x, ss); }
  float inv = 1.f / fmaxf(sqrtf(ss), EPSF);
#pragma unroll
  for (int s = 0; s < 4; ++s) {
    short8v oh;
#pragma unroll
    for (int e = 0; e < 8; ++e) oh[e] = (short)f2bf(v[s*8+e] * inv);
    dst[(size_t)s * MM + pix] = oh;
  }
}

// ------------------------------------------------------------------
// K2: homography (f64) + warped coords per (iv,n,b)
// ------------------------------------------------------------------
__device__ inline void rodrigues_d(const double rv[3], double R[9]) {
  double th = sqrt(rv[0]*rv[0] + rv[1]*rv[1] + rv[2]*rv[2]);
  double thc = fmax(th, 1e-12);
  double kx = rv[0] / thc, ky = rv[1] / thc, kz = rv[2] / thc;
  double st = sin(th), ct = cos(th);
  double Km[9] = { 0.0, -kz,  ky,  kz, 0.0, -kx,  -ky, kx, 0.0 };
  double K2[9];
  for (int r = 0; r < 3; ++r)
    for (int c = 0; c < 3; ++c)
      K2[r*3+c] = Km[r*3+0]*Km[0*3+c] + Km[r*3+1]*Km[1*3+c] + Km[r*3+2]*Km[2*3+c];
  for (int r = 0; r < 3; ++r)
    for (int c = 0; c < 3; ++c)
      R[r*3+c] = (r == c ? 1.0 : 0.0) + st * Km[r*3+c] + (1.0 - ct) * K2[r*3+c];
}
__device__ inline void mm3(const double* A, const double* B, double* C) {
  for (int r = 0; r < 3; ++r)
    for (int c = 0; c < 3; ++c)
      C[r*3+c] = A[r*3+0]*B[0*3+c] + A[r*3+1]*B[1*3+c] + A[r*3+2]*B[2*3+c];
}

__global__ void k_warp(const float* __restrict__ rv_, const float* __restrict__ tv_,
                       const float* __restrict__ nts_, const float* __restrict__ dep_,
                       const float* __restrict__ Ks_, const float* __restrict__ Kin_,
                       const float* __restrict__ osz_, const int* __restrict__ ivl,
                       float2* __restrict__ warped) {
  int slot = blockIdx.x;
  int ivi = slot / (NMAX * BB);
  int rem = slot % (NMAX * BB);
  int n = rem / BB, b = rem % BB;
  int iv = ivl[ivi];
  if (n >= TC - iv) return;
  int q0 = n, q1 = n + iv;
  int t0 = q0 / CAM, c0 = q0 % CAM;
  int t1 = q1 / CAM, c1 = q1 % CAM;
  size_t e0 = (size_t)(t0 * BB + b) * CAM + c0;
  size_t e1 = (size_t)(t1 * BB + b) * CAM + c1;

  double rv0[3], tv0[3], rv1[3], tv1[3], nv[3];
  for (int k = 0; k < 3; ++k) {
    rv0[k] = rv_[e0*3 + k]; tv0[k] = tv_[e0*3 + k];
    rv1[k] = rv_[e1*3 + k]; tv1[k] = tv_[e1*3 + k];
    nv[k]  = nts_[e0*3 + k];
  }
  double d = dep_[e0];
  double K9[9], Ki9[9];
  for (int k = 0; k < 9; ++k) { K9[k] = Ks_[e0*9 + k]; Ki9[k] = Kin_[e0*9 + k]; }

  double R0[9], R1[9], R[9];
  rodrigues_d(rv0, R0);
  rodrigues_d(rv1, R1);
  for (int r = 0; r < 3; ++r)
    for (int c = 0; c < 3; ++c)
      R[r*3+c] = R1[r*3+0]*R0[c*3+0] + R1[r*3+1]*R0[c*3+1] + R1[r*3+2]*R0[c*3+2];
  double tvec[3];
  for (int r = 0; r < 3; ++r)
    tvec[r] = tv1[r] - (R[r*3+0]*tv0[0] + R[r*3+1]*tv0[1] + R[r*3+2]*tv0[2]);
  double Mid[9];
  for (int r = 0; r < 3; ++r)
    for (int c = 0; c < 3; ++c)
      Mid[r*3+c] = R[r*3+c] - tvec[r] * nv[c] / d;
  double T1[9], Hm[9];
  mm3(K9, Mid, T1);
  mm3(T1, Ki9, Hm);

  double osz0 = osz_[e0*2 + 0], osz1 = osz_[e0*2 + 1];
  double s0 = 240.0 / osz0, s1 = 320.0 / osz1;
  double sv[3] = { s1, s0, 1.0 };
  double Hs[9];
  for (int r = 0; r < 3; ++r)
    for (int c = 0; c < 3; ++c)
      Hs[r*3+c] = Hm[r*3+c] * sv[r] / sv[c];

  float2* wout = warped + (size_t)slot * MM;
  for (int cell = threadIdx.x; cell < MM; cell += blockDim.x) {
    double x = (double)((cell % WC) * 8);
    double y = (double)((cell / WC) * 8);
    double wx = Hs[0]*x + Hs[1]*y + Hs[2];
    double wy = Hs[3]*x + Hs[4]*y + Hs[5];
    double wz = Hs[6]*x + Hs[7]*y + Hs[8];
    float z = (float)wz;
    if (fabsf(z) < 1e-8f) z = 1e-8f;
    wout[cell] = make_float2((float)wx / z, (float)wy / z);
  }
}

__device__ inline bool decode_slot(int slot, const int* ivl, int& n, int& b, int& iv) {
  int ivi = slot / (NMAX * BB);
  int rem = slot % (NMAX * BB);
  n = rem / BB; b = rem % BB;
  iv = ivl[ivi];
  return n < TC - iv;
}

__device__ inline float4v s_tile1(short8v ah, short8v bh) {
  float4v acc = {0.f, 0.f, 0.f, 0.f};
  return __builtin_amdgcn_mfma_f32_16x16x32_bf16(ah, bh, acc, 0, 0, 0);
}

// ------------------------------------------------------------------
// K3a: partial row sum-of-squares. wave = 32 rows (2 tiles), half the
// j range (jh). Prefetch depth 2. C/D: col=lane&15, row=(lane>>4)*4+reg.
// ------------------------------------------------------------------
__global__ void __launch_bounds__(64) k_rnorm_p(const short8v* __restrict__ dsp,
                                                const int* __restrict__ ivl,
                                                float* __restrict__ prn) {
  int slot = blockIdx.x, rg = blockIdx.y, jh = blockIdx.z;
  int n, b, iv;
  if (!decode_slot(slot, ivl, n, b, iv)) return;
  int lane = threadIdx.x & 63, q = lane >> 4, li = lane & 15;
  int base = rg * 32;
  bool v1 = (base + 16) < MM;
  int r16a = base, r16b = v1 ? base + 16 : base;
  const short8v* D0 = dsp + (size_t)(n * BB + b) * 4 * MM;
  const short8v* B0 = dsp + (size_t)((n + iv) * BB + b) * 4 * MM + (size_t)q * MM + li;
  short8v ah0 = D0[(size_t)q * MM + r16a + li];
  short8v ah1 = D0[(size_t)q * MM + r16b + li];
  int jt0 = jh * 38, jtN = jh ? JT : 38;
  short8v bA = B0[jt0 * 16];
  short8v bB = B0[min(jt0 + 1, JT - 1) * 16];
  float4v racc0 = {0.f, 0.f, 0.f, 0.f};
  float4v racc1 = {0.f, 0.f, 0.f, 0.f};
#pragma unroll 3
  for (int jt = jt0; jt < jtN; ++jt) {
    short8v bC = B0[min(jt + 2, JT - 1) * 16];
    float4v acc0 = s_tile1(ah0, bA);
    float4v acc1 = s_tile1(ah1, bA);
#pragma unroll
    for (int r = 0; r < 4; ++r) {
      float t0 = fmaxf(acc0[r], 0.f); racc0[r] = fmaf(t0, t0, racc0[r]);
      float t1 = fmaxf(acc1[r], 0.f); racc1[r] = fmaf(t1, t1, racc1[r]);
    }
    bA = bB; bB = bC;
  }
#pragma unroll
  for (int m = 1; m <= 8; m <<= 1)
#pragma unroll
    for (int r = 0; r < 4; ++r) {
      racc0[r] += __shfl_xor(racc0[r], m);
      racc1[r] += __shfl_xor(racc1[r], m);
    }
  if (li == 0) {
    float* o = prn + ((size_t)slot * JSP + jh) * MM;
#pragma unroll
    for (int r = 0; r < 4; ++r) o[r16a + q * 4 + r] = racc0[r];
    if (v1) {
#pragma unroll
      for (int r = 0; r < 4; ++r) o[r16b + q * 4 + r] = racc1[r];
    }
  }
}

// K3b: finisher -> irn = 1/max(sqrt(p0+p1), eps)
__global__ void __launch_bounds__(256) k_rnorm_fin(const float* __restrict__ prn,
                                                   const int* __restrict__ ivl,
                                                   float* __restrict__ irn) {
  int slot = blockIdx.x;
  int n, b, iv;
  if (!decode_slot(slot, ivl, n, b, iv)) return;
  int row = blockIdx.y * 256 + threadIdx.x;
  if (row >= MM) return;
  float p = prn[((size_t)slot * JSP + 0) * MM + row] + prn[((size_t)slot * JSP + 1) * MM + row];
  irn[(size_t)slot * MM + row] = 1.f / fmaxf(sqrtf(p), EPSF);
}

// ------------------------------------------------------------------
// K4a: partial col sum-of-squares of (relu(S)·irn_i). wave = 32 cols,
// half the i range.
// ------------------------------------------------------------------
__global__ void __launch_bounds__(64) k_cnorm_p(const short8v* __restrict__ dsp,
                                                const int* __restrict__ ivl,
                                                const float* __restrict__ irn,
                                                float* __restrict__ pcn) {
  int slot = blockIdx.x, rg = blockIdx.y, jh = blockIdx.z;
  int n, b, iv;
  if (!decode_slot(slot, ivl, n, b, iv)) return;
  int lane = threadIdx.x & 63, q = lane >> 4, li = lane & 15;
  int base = rg * 32;
  bool v1 = (base + 16) < MM;
  int c16a = base, c16b = v1 ? base + 16 : base;
  const short8v* D1 = dsp + (size_t)((n + iv) * BB + b) * 4 * MM;
  const short8v* B0 = dsp + (size_t)(n * BB + b) * 4 * MM + (size_t)q * MM + li;
  short8v ah0 = D1[(size_t)q * MM + c16a + li];
  short8v ah1 = D1[(size_t)q * MM + c16b + li];
  const float* irnS = irn + (size_t)slot * MM + li;
  int jt0 = jh * 38, jtN = jh ? JT : 38;
  short8v bA = B0[jt0 * 16];
  short8v bB = B0[min(jt0 + 1, JT - 1) * 16];
  float irA = irnS[jt0 * 16];
  float irB = irnS[min(jt0 + 1, JT - 1) * 16];
  float4v cacc0 = {0.f, 0.f, 0.f, 0.f};
  float4v cacc1 = {0.f, 0.f, 0.f, 0.f};
#pragma unroll 3
  for (int jt = jt0; jt < jtN; ++jt) {
    short8v bC = B0[min(jt + 2, JT - 1) * 16];
    float irC = irnS[min(jt + 2, JT - 1) * 16];
    float4v acc0 = s_tile1(ah0, bA);
    float4v acc1 = s_tile1(ah1, bA);
#pragma unroll
    for (int r = 0; r < 4; ++r) {
      float t0 = fmaxf(acc0[r], 0.f) * irA; cacc0[r] = fmaf(t0, t0, cacc0[r]);
      float t1 = fmaxf(acc1[r], 0.f) * irA; cacc1[r] = fmaf(t1, t1, cacc1[r]);
    }
    bA = bB; bB = bC; irA = irB; irB = irC;
  }
#pragma unroll
  for (int m = 1; m <= 8; m <<= 1)
#pragma unroll
    for (int r = 0; r < 4; ++r) {
      cacc0[r] += __shfl_xor(cacc0[r], m);
      cacc1[r] += __shfl_xor(cacc1[r], m);
    }
  if (li == 0) {
    float* o = pcn + ((size_t)slot * JSP + jh) * MM;
#pragma unroll
    for (int r = 0; r < 4; ++r) o[c16a + q * 4 + r] = cacc0[r];
    if (v1) {
#pragma unroll
      for (int r = 0; r < 4; ++r) o[c16b + q * 4 + r] = cacc1[r];
    }
  }
}

// K4b: finisher -> icn
__global__ void __launch_bounds__(256) k_cnorm_fin(const float* __restrict__ pcn,
                                                   const int* __restrict__ ivl,
                                                   float* __restrict__ icn) {
  int slot = blockIdx.x;
  int n, b, iv;
  if (!decode_slot(slot, ivl, n, b, iv)) return;
  int col = blockIdx.y * 256 + threadIdx.x;
  if (col >= MM) return;
  float p = pcn[((size_t)slot * JSP + 0) * MM + col] + pcn[((size_t)slot * JSP + 1) * MM + col];
  icn[(size_t)slot * MM + col] = 1.f / fmaxf(sqrtf(p), EPSF);
}

// ------------------------------------------------------------------
// K5: loss, mask-free hot loop; wave = 32 rows, half the j range.
// ------------------------------------------------------------------
__global__ void __launch_bounds__(64) k_loss(const short8v* __restrict__ dsp,
                                             const int* __restrict__ ivl,
                                             const float* __restrict__ irn,
                                             const float* __restrict__ icn,
                                             double* __restrict__ partials) {
  int slot = blockIdx.x, rg = blockIdx.y, jh = blockIdx.z;
  int lane = threadIdx.x & 63;
  size_t pidx = ((size_t)slot * RG + rg) * JSP + jh;
  int n, b, iv;
  if (!decode_slot(slot, ivl, n, b, iv)) {
    if (lane == 0) partials[pidx] = 0.0;
    return;
  }
  int q = lane >> 4, li = lane & 15;
  int base = rg * 32;
  bool v1 = (base + 16) < MM;
  int r16a = base, r16b = v1 ? base + 16 : base;
  const short8v* D0 = dsp + (size_t)(n * BB + b) * 4 * MM;
  const short8v* B0 = dsp + (size_t)((n + iv) * BB + b) * 4 * MM + (size_t)q * MM + li;
  short8v ah0 = D0[(size_t)q * MM + r16a + li];
  short8v ah1 = D0[(size_t)q * MM + r16b + li];
  float uA[4], uB[4];
#pragma unroll
  for (int r = 0; r < 4; ++r) {
    uA[r] = irn[(size_t)slot * MM + r16a + q * 4 + r];
    uB[r] = v1 ? irn[(size_t)slot * MM + r16b + q * 4 + r] : 0.f;
  }
  const float* icnS = icn + (size_t)slot * MM + li;
  int jt0 = jh * 38, jtN = jh ? JT : 38;
  short8v bA = B0[jt0 * 16];
  short8v bB = B0[min(jt0 + 1, JT - 1) * 16];
  float icA = icnS[jt0 * 16];
  float icB = icnS[min(jt0 + 1, JT - 1) * 16];
  float lacc = 0.f;
#pragma unroll 3
  for (int jt = jt0; jt < jtN; ++jt) {
    short8v bC = B0[min(jt + 2, JT - 1) * 16];
    float icC = icnS[min(jt + 2, JT - 1) * 16];
    float4v acc0 = s_tile1(ah0, bA);
    float4v acc1 = s_tile1(ah1, bA);
#pragma unroll
    for (int r = 0; r < 4; ++r) {
      lacc += fmaxf(fmaf(acc0[r], icA * uA[r], -0.2f), 0.f);
      lacc += fmaxf(fmaf(acc1[r], icA * uB[r], -0.2f), 0.f);
    }
    bA = bB; bB = bC; icA = icB; icB = icC;
  }
#pragma unroll
  for (int off = 32; off > 0; off >>= 1) lacc += __shfl_xor(lacc, off);
  if (lane == 0) partials[pidx] = (double)lacc;
}

// ------------------------------------------------------------------
// K5b: correction for masked cells (<=4 per row), hi-only descriptors.
// ------------------------------------------------------------------
__global__ void __launch_bounds__(256) k_corr(const short8v* __restrict__ dsp,
                                              const int* __restrict__ ivl,
                                              const float* __restrict__ irn,
                                              const float* __restrict__ icn,
                                              const float2* __restrict__ warped,
                                              double* __restrict__ partials2) {
  __shared__ double swsum[4];
  int slot = blockIdx.x, tile = blockIdx.y;
  int t = threadIdx.x;
  int n, b, iv;
  bool valid = decode_slot(slot, ivl, n, b, iv);
  double corr = 0.0;
  int row = tile * 256 + t;
  if (valid && row < MM) {
    float2 wp = warped[(size_t)slot * MM + row];
    int kx0 = max(0, (int)ceilf((wp.x - 7.5f) * 0.125f));
    int kx1 = min(WC - 1, (int)floorf((wp.x + 7.5f) * 0.125f));
    int ky0 = max(0, (int)ceilf((wp.y - 7.5f) * 0.125f));
    int ky1 = min(HC - 1, (int)floorf((wp.y + 7.5f) * 0.125f));
    if (kx0 <= kx1 && ky0 <= ky1) {
      const short8v* D0 = dsp + (size_t)(n * BB + b) * 4 * MM;
      const short8v* D1 = dsp + (size_t)((n + iv) * BB + b) * 4 * MM;
      float a[CF];
#pragma unroll
      for (int qq = 0; qq < 4; ++qq) {
        short8v h = D0[(size_t)qq * MM + row];
#pragma unroll
        for (int e = 0; e < 8; ++e) a[qq * 8 + e] = bf2f((unsigned short)h[e]);
      }
      float ir = irn[(size_t)slot * MM + row];
      float fcorr = 0.f;
      for (int ky = ky0; ky <= ky1; ++ky) {
        for (int kx = kx0; kx <= kx1; ++kx) {
          float dx = (float)(kx * 8) - wp.x;
          float dy = (float)(ky * 8) - wp.y;
          if (fmaf(dx, dx, dy * dy) <= 56.25f) {
            int j = ky * WC + kx;
            float dot = 0.f;
#pragma unroll
            for (int qq = 0; qq < 4; ++qq) {
              short8v h1 = D1[(size_t)qq * MM + j];
#pragma unroll
              for (int e = 0; e < 8; ++e)
                dot = fmaf(a[qq * 8 + e], bf2f((unsigned short)h1[e]), dot);
            }
            float s = fmaxf(dot, 0.f);
            float D = s * ir * icn[(size_t)slot * MM + j];
            fcorr += 0.05f * fmaxf(1.f - D, 0.f) - fmaxf(D - 0.2f, 0.f);
          }
        }
      }
      corr = (double)fcorr;
    }
  }
#pragma unroll
  for (int off = 32; off > 0; off >>= 1) corr += __shfl_down(corr, off);
  int wid = t >> 6, lane = t & 63;
  if (lane == 0) swsum[wid] = corr;
  __syncthreads();
  if (t == 0) partials2[(size_t)slot * CT + tile] = swsum[0] + swsum[1] + swsum[2] + swsum[3];
}

// ------------------------------------------------------------------
// K6: final reduction
// ------------------------------------------------------------------
__global__ void k_final(const double* __restrict__ partials,
                        const double* __restrict__ partials2,
                        const int* __restrict__ ivl,
                        int niv, float* __restrict__ out) {
  int lane = threadIdx.x; // 64 threads
  double total = 0.0;
  for (int ivi = 0; ivi < niv; ++ivi) {
    double local = 0.0;
    int base1 = ivi * NMAX * BB * RG * JSP;
    for (int p = lane; p < NMAX * BB * RG * JSP; p += 64) local += partials[base1 + p];
    int base2 = ivi * NMAX * BB * CT;
    for (int p = lane; p < NMAX * BB * CT; p += 64) local += partials2[base2 + p];
    for (int off = 32; off > 0; off >>= 1) local += __shfl_down(local, off);
    int N = TC - ivl[ivi];
    total += local / ((double)N * BB * (double)MM * (double)MM);
  }
  if (lane == 0) out[0] = (float)(total / (double)niv);
}

// ------------------------------------------------------------------
extern "C" void kernel_launch(void* const* d_in, const int* in_sizes, int n_in,
                              void* d_out, int out_size, void* d_ws, size_t ws_size,
                              hipStream_t stream) {
  const float* pred = (const float*)d_in[0];
  const float* rv   = (const float*)d_in[1];
  const float* tv   = (const float*)d_in[2];
  const float* nts  = (const float*)d_in[3];
  const float* dep  = (const float*)d_in[4];
  const float* Ks   = (const float*)d_in[5];
  const float* Kin  = (const float*)d_in[6];
  const float* osz  = (const float*)d_in[7];
  const int*   ivl  = (const int*)d_in[8];
  int niv = in_sizes[8];
  int slots = niv * NMAX * BB;

  char* ws = (char*)d_ws;
  size_t off = 0;
  short8v* dsp = (short8v*)(ws + off);  off += (size_t)TC * BB * 4 * MM * 16;
  float2* warped = (float2*)(ws + off); off += (size_t)slots * MM * 8;
  float* prn = (float*)(ws + off);      off += (size_t)slots * JSP * MM * 4;
  float* pcn = (float*)(ws + off);      off += (size_t)slots * JSP * MM * 4;
  float* irn = (float*)(ws + off);      off += (size_t)slots * MM * 4;
  float* icn = (float*)(ws + off);      off += (size_t)slots * MM * 4;
  off = (off + 255) & ~(size_t)255;
  double* partials = (double*)(ws + off);  off += (size_t)slots * RG * JSP * 8;
  double* partials2 = (double*)(ws + off); off += (size_t)slots * CT * 8;

  hipLaunchKernelGGL(k_split, dim3(TC * BB, 5), dim3(256), 0, stream, pred, dsp);
  hipLaunchKernelGGL(k_warp, dim3(slots), dim3(64), 0, stream,
                     rv, tv, nts, dep, Ks, Kin, osz, ivl, warped);
  dim3 sgrid(slots, RG, JSP);
  dim3 fgrid(slots, CT);
  hipLaunchKernelGGL(k_rnorm_p, sgrid, dim3(64), 0, stream, dsp, ivl, prn);
  hipLaunchKernelGGL(k_rnorm_fin, fgrid, dim3(256), 0, stream, prn, ivl, irn);
  hipLaunchKernelGGL(k_cnorm_p, sgrid, dim3(64), 0, stream, dsp, ivl, irn, pcn);
  hipLaunchKernelGGL(k_cnorm_fin, fgrid, dim3(256), 0, stream, pcn, ivl, icn);
  hipLaunchKernelGGL(k_loss, sgrid, dim3(64), 0, stream, dsp, ivl, irn, icn, partials);
  hipLaunchKernelGGL(k_corr, fgrid, dim3(256), 0, stream,
                     dsp, ivl, irn, icn, warped, partials2);
  hipLaunchKernelGGL(k_final, dim3(1), dim3(64), 0, stream,
                     partials, partials2, ivl, niv, (float*)d_out);
}